// Round 1
// baseline (786.019 us; speedup 1.0000x reference)
//
#include <hip/hip_runtime.h>

#define BB 4
#define SS 2048
#define DD 2048
#define HH 16
#define HD 128
#define D3 6144

typedef __attribute__((ext_vector_type(8))) short short8;
typedef __attribute__((ext_vector_type(4))) float float4v;

#define MFMA16(a, b, c) __builtin_amdgcn_mfma_f32_16x16x32_bf16(a, b, c, 0, 0, 0)

// async global->LDS, 16B per lane; LDS dest = wave-uniform base + lane*16
#define GLL16(g, l)                                                     \
    __builtin_amdgcn_global_load_lds(                                   \
        (__attribute__((address_space(1))) void*)(g),                   \
        (__attribute__((address_space(3))) void*)(l), 16, 0, 0)

__device__ __forceinline__ unsigned short f2b(float f) {
    union { float f; unsigned u; } v;
    v.f = f;
    unsigned r = v.u + 0x7FFFu + ((v.u >> 16) & 1u);  // RNE
    return (unsigned short)(r >> 16);
}
__device__ __forceinline__ float b2f(unsigned short h) {
    union { unsigned u; float f; } v;
    v.u = ((unsigned)h) << 16;
    return v.f;
}

// ---------------- cast fp32 -> bf16 (4 elems/thread) ----------------
__global__ void cast_f32_bf16(const float* __restrict__ in,
                              unsigned short* __restrict__ out) {
    int i = (blockIdx.x * 256 + threadIdx.x) * 4;
    float4 v = *(const float4*)(in + i);
    ushort4 o;
    o.x = f2b(v.x); o.y = f2b(v.y); o.z = f2b(v.z); o.w = f2b(v.w);
    *(ushort4*)(out + i) = o;
}

// ------------- transpose + cast: in (R x C) fp32 -> out (C x R) bf16 -------------
__global__ void transpose_cast(const float* __restrict__ in,
                               unsigned short* __restrict__ out, int R, int C) {
    __shared__ float tile[32][33];
    int c0 = blockIdx.x * 32, r0 = blockIdx.y * 32;
    int tc = threadIdx.x & 31, tr = threadIdx.x >> 5;
#pragma unroll
    for (int i = 0; i < 4; ++i) {
        int r = tr + i * 8;
        tile[r][tc] = in[(size_t)(r0 + r) * C + c0 + tc];
    }
    __syncthreads();
#pragma unroll
    for (int i = 0; i < 4; ++i) {
        int wr = tr + i * 8;
        out[(size_t)(c0 + wr) * R + r0 + tc] = f2b(tile[tc][wr]);
    }
}

// ---------- transpose V within qkv -> vT[bh][d][s] (bf16) ----------
__global__ void vtrans(const unsigned short* __restrict__ qkv,
                       unsigned short* __restrict__ vT) {
    __shared__ unsigned short tile[32][33];
    int bh = blockIdx.z, b = bh >> 4, h = bh & 15;
    int s0 = blockIdx.x * 32, d0 = blockIdx.y * 32;
    int tc = threadIdx.x & 31, tr = threadIdx.x >> 5;
    const unsigned short* src = qkv + (size_t)b * SS * D3 + 4096 + h * HD;
#pragma unroll
    for (int i = 0; i < 4; ++i) {
        int sl = tr + i * 8;
        tile[sl][tc] = src[(size_t)(s0 + sl) * D3 + d0 + tc];
    }
    __syncthreads();
    unsigned short* dst = vT + (size_t)bh * HD * SS;
#pragma unroll
    for (int i = 0; i < 4; ++i) {
        int dl = tr + i * 8;
        dst[(size_t)(d0 + dl) * SS + s0 + tc] = tile[tc][dl];
    }
}

// ============ 256x256 8-phase bf16 GEMM: C = A (MxK) * Bt^T + bias ============
// 8 waves (2M x 4N), BK=64, 128KiB LDS double-buffer, XOR slot-swizzle (T2),
// counted vmcnt (T3/T4), setprio around MFMA clusters (T5), XCD swizzle (T1).
// Per wave: 128x64 output = acc[8][4] float4v. 4 phases per K-tile:
//   P0: stage A(next) | ds_read A-half0+B-half0 | bar | lgkm0 | 16 MFMA | bar
//   P1: stage B(next) | ds_read B-half1         | bar | lgkm0 | 16 MFMA | bar
//   P2:                 ds_read A-half1         | bar | lgkm0 | 16 MFMA | bar
//   P3:                                                        16 MFMA | bar
// Buffer-ready fence: vmcnt(4) + barrier at P0 (drains prev iter's 8 loads,
// leaves this P0's 4 in flight). Stages into buf X only issued after the
// barrier closing all reads of buf X (P2-bar of the previous use).
template <int BF16OUT>
__global__ __launch_bounds__(512, 2) void gemm256(
    const unsigned short* __restrict__ A,   // M x K bf16
    const unsigned short* __restrict__ Bt,  // N x K bf16
    const float* __restrict__ bias,         // N fp32
    void* __restrict__ Cout, int M, int N, int K) {
    __shared__ unsigned short As[2][256 * 64];  // 64 KiB
    __shared__ unsigned short Bs[2][256 * 64];  // 64 KiB

    // bijective XCD swizzle (grid % 8 == 0 for both call sites)
    const int nbx = N >> 8;
    const int lin = blockIdx.y * nbx + blockIdx.x;
    const int cpx = (nbx * (M >> 8)) >> 3;
    const int wg = (lin & 7) * cpx + (lin >> 3);
    const int n0 = (wg % nbx) * 256, m0 = (wg / nbx) * 256;

    const int t = threadIdx.x, lane = t & 63, w = t >> 6;
    const int quad = lane >> 4, lr = lane & 15;
    const int wm = (w >> 2) * 128, wn = (w & 3) * 64;

    // staging: per round, wave w covers 8 rows (w*32+r*8..+7), 64 k-cols.
    // lane -> row-in-8 = lane>>3, 16B slot = lane&7; source col pre-swizzled
    // by (slot ^ row&7) so linear LDS + swizzled ds_read agree (rule #21).
    const int sr = lane >> 3;
    const int ss = (lane & 7) ^ sr;
    const unsigned short* Ag = A + (size_t)(m0 + w * 32 + sr) * K + ss * 8;
    const unsigned short* Bg = Bt + (size_t)(n0 + w * 32 + sr) * K + ss * 8;

    float4v acc[8][4] = {};
    short8 af[4][2], b0[2][2], b1[2][2];

#define STAGE_A(buf, k0)                                                     \
    do {                                                                     \
        _Pragma("unroll") for (int r = 0; r < 4; ++r)                        \
            GLL16(Ag + (k0) + (size_t)r * 8 * K,                             \
                  &As[buf][(w * 32 + r * 8) * 64]);                          \
    } while (0)
#define STAGE_B(buf, k0)                                                     \
    do {                                                                     \
        _Pragma("unroll") for (int r = 0; r < 4; ++r)                        \
            GLL16(Bg + (k0) + (size_t)r * 8 * K,                             \
                  &Bs[buf][(w * 32 + r * 8) * 64]);                          \
    } while (0)
#define LDA(dst, mh)                                                         \
    do {                                                                     \
        _Pragma("unroll") for (int i = 0; i < 4; ++i)                        \
            _Pragma("unroll") for (int kk = 0; kk < 2; ++kk)                 \
                dst[i][kk] = *(const short8*)&As[cur][                       \
                    (wm + (mh)*64 + i * 16 + lr) * 64 +                      \
                    (((kk * 4 + quad) ^ (lr & 7)) * 8)];                     \
    } while (0)
#define LDB(dst, nh)                                                         \
    do {                                                                     \
        _Pragma("unroll") for (int j = 0; j < 2; ++j)                        \
            _Pragma("unroll") for (int kk = 0; kk < 2; ++kk)                 \
                dst[j][kk] = *(const short8*)&Bs[cur][                       \
                    (wn + (nh)*32 + j * 16 + lr) * 64 +                      \
                    (((kk * 4 + quad) ^ (lr & 7)) * 8)];                     \
    } while (0)
#define MM(ar, br, io, jo)                                                   \
    do {                                                                     \
        __builtin_amdgcn_s_setprio(1);                                       \
        _Pragma("unroll") for (int kk = 0; kk < 2; ++kk)                     \
            _Pragma("unroll") for (int i = 0; i < 4; ++i)                    \
                _Pragma("unroll") for (int j = 0; j < 2; ++j)                \
                    acc[(io) + i][(jo) + j] = MFMA16(                        \
                        ar[i][kk], br[j][kk], acc[(io) + i][(jo) + j]);      \
        __builtin_amdgcn_s_setprio(0);                                       \
    } while (0)

    const int NT = K >> 6;
    STAGE_A(0, 0);
    STAGE_B(0, 0);

    for (int tk = 0; tk < NT; ++tk) {
        const int cur = tk & 1, nxt = cur ^ 1;
        // last iter re-stages tile 0 into the dead buffer: keeps vmcnt(4)
        // bookkeeping uniform; drained after the loop.
        const size_t k0n = (size_t)(tk + 1 == NT ? 0 : tk + 1) << 6;

        // ---- P0 ----
        STAGE_A(nxt, k0n);
        asm volatile("s_waitcnt vmcnt(4)" ::: "memory");
        __builtin_amdgcn_s_barrier();           // buf[cur] fully landed
        __builtin_amdgcn_sched_barrier(0);
        LDA(af, 0);
        LDB(b0, 0);
        __builtin_amdgcn_s_barrier();
        asm volatile("s_waitcnt lgkmcnt(0)" ::: "memory");
        __builtin_amdgcn_sched_barrier(0);
        MM(af, b0, 0, 0);
        __builtin_amdgcn_s_barrier();
        // ---- P1 ----
        STAGE_B(nxt, k0n);
        LDB(b1, 1);
        __builtin_amdgcn_s_barrier();
        asm volatile("s_waitcnt lgkmcnt(0)" ::: "memory");
        __builtin_amdgcn_sched_barrier(0);
        MM(af, b1, 0, 2);
        __builtin_amdgcn_s_barrier();
        // ---- P2 ----
        LDA(af, 1);
        __builtin_amdgcn_s_barrier();
        asm volatile("s_waitcnt lgkmcnt(0)" ::: "memory");
        __builtin_amdgcn_sched_barrier(0);
        MM(af, b0, 4, 0);
        __builtin_amdgcn_s_barrier();
        // ---- P3 ----
        MM(af, b1, 4, 2);
        __builtin_amdgcn_s_barrier();
    }
    // drain wrap-around dummy stage before LDS is freed at endpgm
    asm volatile("s_waitcnt vmcnt(0)" ::: "memory");

#pragma unroll
    for (int jj = 0; jj < 4; ++jj) {
        const int n = n0 + wn + jj * 16 + lr;
        const float bv = bias[n];
#pragma unroll
        for (int ii = 0; ii < 8; ++ii)
#pragma unroll
            for (int r = 0; r < 4; ++r) {
                const int m = m0 + wm + ii * 16 + quad * 4 + r;
                const float v = acc[ii][jj][r] + bv;
                if (BF16OUT)
                    ((unsigned short*)Cout)[(size_t)m * N + n] = f2b(v);
                else
                    ((float*)Cout)[(size_t)m * N + n] = v;
            }
    }
#undef STAGE_A
#undef STAGE_B
#undef LDA
#undef LDB
#undef MM
}

// ---------------- RoPE in-place on q,k of qkv (bf16), 4 pairs/thread -----------
__global__ void rope_kernel(unsigned short* __restrict__ qkv) {
    int tid = blockIdx.x * 256 + threadIdx.x;  // 2,097,152 threads
    int i4 = tid & 15;
    int h = (tid >> 4) & 15;
    int s = (tid >> 8) & 2047;
    int b = tid >> 19;
    size_t off = ((size_t)(b * SS + s)) * D3 + h * HD + i4 * 8;
    unsigned short* q = qkv + off;
    unsigned short* k = q + 2048;
    short8 qv = *(short8*)q, kv = *(short8*)k;
    const float L2IF = 0.2076205059304601f;    // log2(10000)/64
    const float R2PI = 0.15915494309189535f;   // 1/(2*pi)
    short8 qo, ko;
#pragma unroll
    for (int j = 0; j < 4; ++j) {
        int i = i4 * 4 + j;
        float invr = exp2f(-(float)i * L2IF) * R2PI;
        float rev = (float)s * invr;
        float rr = rev - floorf(rev);
        float sn = __builtin_amdgcn_sinf(rr);
        float cs = __builtin_amdgcn_cosf(rr);
        float a0 = b2f((unsigned short)qv[2 * j]);
        float a1 = b2f((unsigned short)qv[2 * j + 1]);
        qo[2 * j] = (short)f2b(a0 * cs - a1 * sn);
        qo[2 * j + 1] = (short)f2b(a1 * cs + a0 * sn);
        float c0 = b2f((unsigned short)kv[2 * j]);
        float c1 = b2f((unsigned short)kv[2 * j + 1]);
        ko[2 * j] = (short)f2b(c0 * cs - c1 * sn);
        ko[2 * j + 1] = (short)f2b(c1 * cs + c0 * sn);
    }
    *(short8*)q = qo;
    *(short8*)k = ko;
}

// ---------------- flash attention (causal), S^T form, 1-barrier pipeline -------
// grid (8, B*H): block handles q-block pair (x, 15-x) -> uniform 34 k-tiles.
// Ks/Vs double-buffered: prefetch tile i+1 while computing tile i.
__global__ __launch_bounds__(256) void attn_kernel(
    const unsigned short* __restrict__ qkv,
    const unsigned short* __restrict__ vT,
    unsigned short* __restrict__ ctx) {
    __shared__ unsigned short Ks[2][64 * 128];  // [key][dim] swizzled chunks
    __shared__ unsigned short Vs[2][128 * 64];  // [dim][key] swizzled chunks
    __shared__ unsigned short PT[4][32][40];    // per-wave P^T rows=q, 32-key chunk
    const int bh = blockIdx.y, b = bh >> 4, h = bh & 15;
    const int t = threadIdx.x, w = t >> 6, lane = t & 63;
    const int quad = lane >> 4, lr = lane & 15;
    const unsigned short* qbase = qkv + (size_t)b * SS * D3 + h * HD;
    const unsigned short* kbase = qbase + 2048;
    const unsigned short* vtb = vT + (size_t)bh * HD * SS;
    const float SCL2E = 0.12751741769976451f;   // (1/sqrt(128))*log2(e)
    const float NB16 = -23.083120654223414f;    // -16*log2(e)
    const int q0a = blockIdx.x * 128;
    const int q0b = (15 - (int)blockIdx.x) * 128;
    const int nta = (q0a >> 6) + 2, ntb = (q0b >> 6) + 2, ntot = nta + ntb;
    const int kr = lane >> 4, kg = lane & 15;
    const int vr = lane >> 3, vg = lane & 7;

    auto stage = [&](int k0, int bi) {
        unsigned short* KD = Ks[bi];
        unsigned short* VD = Vs[bi];
#pragma unroll
        for (int u = 0; u < 4; ++u) {
            int row = w * 16 + u * 4 + kr;
            int g = kg ^ (row & 15);
            GLL16(kbase + (size_t)(k0 + row) * D3 + g * 8,
                  &KD[(w * 16 + u * 4) * 128]);
        }
#pragma unroll
        for (int u = 0; u < 4; ++u) {
            int row = w * 32 + u * 8 + vr;
            int g = vg ^ (row & 7);
            GLL16(vtb + (size_t)row * SS + k0 + g * 8,
                  &VD[(w * 32 + u * 8) * 64]);
        }
    };

    int wq = q0a + w * 32;
    short8 qf[2][4];
#pragma unroll
    for (int m = 0; m < 2; ++m)
#pragma unroll
        for (int c = 0; c < 4; ++c)
            qf[m][c] = *(const short8*)(qbase + (size_t)(wq + m * 16 + lr) * D3 +
                                        c * 32 + quad * 8);

    float4v o[2][8] = {};
    float l_lane[2] = {0.f, 0.f};

    auto epilogue = [&]() {
#pragma unroll
        for (int m = 0; m < 2; ++m) {
            float l = l_lane[m];
            l += __shfl_xor(l, 16);
            l += __shfl_xor(l, 32);  // all lanes now hold l for q=lr
#pragma unroll
            for (int r = 0; r < 4; ++r) {
                float linv = 1.0f / __shfl(l, quad * 4 + r);
#pragma unroll
                for (int dc = 0; dc < 8; ++dc) {
                    float val = o[m][dc][r] * linv;
                    ctx[(size_t)(b * SS + wq + m * 16 + quad * 4 + r) * DD +
                        h * HD + dc * 16 + lr] = f2b(val);
                }
            }
        }
    };

    stage(0, 0);  // prologue prefetch

    for (int it = 0; it < ntot; ++it) {
        __syncthreads();  // drains stage(it) loads; fences buffer reuse
        int nit = it + 1;
        if (nit < ntot) stage((nit < nta ? nit : nit - nta) * 64, nit & 1);
        int k0 = (it < nta ? it : it - nta) * 64;
        const unsigned short* KB = Ks[it & 1];
        const unsigned short* VB = Vs[it & 1];

        if (k0 <= wq + 31) {
            // S^T = K Q^T : rows=key, cols=q. 4 key-subtiles x 2 q-subtiles.
            float4v sc[2][4] = {};
#pragma unroll
            for (int c = 0; c < 4; ++c) {
                short8 kf[4];
#pragma unroll
                for (int ks = 0; ks < 4; ++ks)
                    kf[ks] = *(const short8*)&KB[(ks * 16 + lr) * 128 +
                                                 (((c * 4 + quad) ^ lr) * 8)];
#pragma unroll
                for (int ks = 0; ks < 4; ++ks) {
                    sc[0][ks] = MFMA16(kf[ks], qf[0][c], sc[0][ks]);
                    sc[1][ks] = MFMA16(kf[ks], qf[1][c], sc[1][ks]);
                }
            }
            const bool nm = (k0 + 63 > wq);
#pragma unroll
            for (int kc = 0; kc < 2; ++kc) {
                // softmax on 32-key chunk; lane holds keys quad*4+r of q=lr
#pragma unroll
                for (int m = 0; m < 2; ++m)
#pragma unroll
                    for (int ks2 = 0; ks2 < 2; ++ks2) {
                        int ks = kc * 2 + ks2;
                        unsigned pk[2];
#pragma unroll
                        for (int rp = 0; rp < 2; ++rp) {
                            unsigned lo = 0, hi = 0;
#pragma unroll
                            for (int rr = 0; rr < 2; ++rr) {
                                int r = rp * 2 + rr;
                                float p = exp2f(fmaf(sc[m][ks][r], SCL2E, NB16));
                                if (nm) {
                                    int key = k0 + ks * 16 + quad * 4 + r;
                                    if (key > wq + m * 16 + lr) p = 0.0f;
                                }
                                l_lane[m] += p;
                                union { float f; unsigned u; } pu;
                                pu.f = p;
                                if (rr == 0) lo = pu.u >> 16;
                                else hi = pu.u >> 16;
                            }
                            pk[rp] = lo | (hi << 16);
                        }
                        uint2 pkk = {pk[0], pk[1]};
                        *(uint2*)&PT[w][m * 16 + lr][ks2 * 16 + quad * 4] = pkk;
                    }
                // O += P V for this 32-key chunk
                short8 pf0 = *(const short8*)&PT[w][lr][quad * 8];
                short8 pf1 = *(const short8*)&PT[w][16 + lr][quad * 8];
#pragma unroll
                for (int dc = 0; dc < 8; ++dc) {
                    short8 vf = *(const short8*)&VB[(dc * 16 + lr) * 64 +
                                                    (((kc * 4 + quad) ^ (lr & 7)) * 8)];
                    o[0][dc] = MFMA16(pf0, vf, o[0][dc]);
                    o[1][dc] = MFMA16(pf1, vf, o[1][dc]);
                }
            }
        }

        if (it == nta - 1) {
            // finish q-block a, switch to q-block b
            epilogue();
#pragma unroll
            for (int m = 0; m < 2; ++m) {
                l_lane[m] = 0.f;
#pragma unroll
                for (int dc = 0; dc < 8; ++dc) o[m][dc] = (float4v){0, 0, 0, 0};
            }
            wq = q0b + w * 32;
#pragma unroll
            for (int m = 0; m < 2; ++m)
#pragma unroll
                for (int c = 0; c < 4; ++c)
                    qf[m][c] = *(const short8*)(qbase +
                                                (size_t)(wq + m * 16 + lr) * D3 +
                                                c * 32 + quad * 8);
        }
    }
    epilogue();
}

extern "C" void kernel_launch(void* const* d_in, const int* in_sizes, int n_in,
                              void* d_out, int out_size, void* d_ws, size_t ws_size,
                              hipStream_t stream) {
    const float* x = (const float*)d_in[0];
    const float* Wqkv_w = (const float*)d_in[2];
    const float* Wqkv_b = (const float*)d_in[3];
    const float* Wout_w = (const float*)d_in[4];
    const float* Wout_b = (const float*)d_in[5];
    float* out = (float*)d_out;

    unsigned short* x_bf = (unsigned short*)d_ws;   // 16,777,216 el (reused as vT)
    unsigned short* wqkv_t = x_bf + 16777216;       // 12,582,912 el
    unsigned short* wout_t = wqkv_t + 12582912;     //  4,194,304 el
    unsigned short* qkv = wout_t + 4194304;         // 50,331,648 el
    unsigned short* ctx = qkv + 50331648;           // 16,777,216 el
    unsigned short* vT = x_bf;                      // alias: x_bf dead after QKV GEMM
    // total ws: 100,663,296 el * 2B = 192 MiB

    cast_f32_bf16<<<16384, 256, 0, stream>>>(x, x_bf);
    transpose_cast<<<dim3(192, 64), 256, 0, stream>>>(Wqkv_w, wqkv_t, 2048, 6144);
    transpose_cast<<<dim3(64, 64), 256, 0, stream>>>(Wout_w, wout_t, 2048, 2048);
    gemm256<1><<<dim3(24, 32), 512, 0, stream>>>(x_bf, wqkv_t, Wqkv_b, qkv,
                                                 8192, 6144, 2048);
    rope_kernel<<<8192, 256, 0, stream>>>(qkv);
    vtrans<<<dim3(64, 4, 64), 256, 0, stream>>>(qkv, vT);
    attn_kernel<<<dim3(8, 64), 256, 0, stream>>>(qkv, vT, ctx);
    gemm256<0><<<dim3(8, 32), 512, 0, stream>>>(ctx, wout_t, Wout_b, out,
                                                8192, 2048, 2048);
}

// Round 4
// 737.267 us; speedup vs baseline: 1.0661x; 1.0661x over previous
//
#include <hip/hip_runtime.h>

#define BB 4
#define SS 2048
#define DD 2048
#define HH 16
#define HD 128
#define D3 6144

typedef __attribute__((ext_vector_type(8))) short short8;
typedef __attribute__((ext_vector_type(4))) float float4v;

#define MFMA16(a, b, c) __builtin_amdgcn_mfma_f32_16x16x32_bf16(a, b, c, 0, 0, 0)

// async global->LDS, 16B per lane; LDS dest = wave-uniform base + lane*16
#define GLL16(g, l)                                                     \
    __builtin_amdgcn_global_load_lds(                                   \
        (__attribute__((address_space(1))) void*)(g),                   \
        (__attribute__((address_space(3))) void*)(l), 16, 0, 0)

__device__ __forceinline__ unsigned short f2b(float f) {
    union { float f; unsigned u; } v;
    v.f = f;
    unsigned r = v.u + 0x7FFFu + ((v.u >> 16) & 1u);  // RNE
    return (unsigned short)(r >> 16);
}
__device__ __forceinline__ float b2f(unsigned short h) {
    union { unsigned u; float f; } v;
    v.u = ((unsigned)h) << 16;
    return v.f;
}

// ---------------- cast fp32 -> bf16 (4 elems/thread) ----------------
__global__ void cast_f32_bf16(const float* __restrict__ in,
                              unsigned short* __restrict__ out) {
    int i = (blockIdx.x * 256 + threadIdx.x) * 4;
    float4 v = *(const float4*)(in + i);
    ushort4 o;
    o.x = f2b(v.x); o.y = f2b(v.y); o.z = f2b(v.z); o.w = f2b(v.w);
    *(ushort4*)(out + i) = o;
}

// ------------- transpose + cast: in (R x C) fp32 -> out (C x R) bf16 -------------
__global__ void transpose_cast(const float* __restrict__ in,
                               unsigned short* __restrict__ out, int R, int C) {
    __shared__ float tile[32][33];
    int c0 = blockIdx.x * 32, r0 = blockIdx.y * 32;
    int tc = threadIdx.x & 31, tr = threadIdx.x >> 5;
#pragma unroll
    for (int i = 0; i < 4; ++i) {
        int r = tr + i * 8;
        tile[r][tc] = in[(size_t)(r0 + r) * C + c0 + tc];
    }
    __syncthreads();
#pragma unroll
    for (int i = 0; i < 4; ++i) {
        int wr = tr + i * 8;
        out[(size_t)(c0 + wr) * R + r0 + tc] = f2b(tile[tc][wr]);
    }
}

// ---------- transpose V within qkv -> vT[bh][d][s] (bf16) ----------
__global__ void vtrans(const unsigned short* __restrict__ qkv,
                       unsigned short* __restrict__ vT) {
    __shared__ unsigned short tile[32][33];
    int bh = blockIdx.z, b = bh >> 4, h = bh & 15;
    int s0 = blockIdx.x * 32, d0 = blockIdx.y * 32;
    int tc = threadIdx.x & 31, tr = threadIdx.x >> 5;
    const unsigned short* src = qkv + (size_t)b * SS * D3 + 4096 + h * HD;
#pragma unroll
    for (int i = 0; i < 4; ++i) {
        int sl = tr + i * 8;
        tile[sl][tc] = src[(size_t)(s0 + sl) * D3 + d0 + tc];
    }
    __syncthreads();
    unsigned short* dst = vT + (size_t)bh * HD * SS;
#pragma unroll
    for (int i = 0; i < 4; ++i) {
        int dl = tr + i * 8;
        dst[(size_t)(d0 + dl) * SS + s0 + tc] = tile[tc][dl];
    }
}

// ============ 256x256 bf16 GEMM, ring-4 pipelined: C = A * Bt^T + bias ============
// 8 waves (2M x 4N), BK=32, 4-deep LDS tile ring (4 x 32 KiB = 128 KiB),
// counted vmcnt(8) once per K-tile (T3/T4), XOR slot-swizzle (T2), setprio (T5).
//
// Ring ledger (full-tile granularity; uniform across waves):
//   iter t reads buf[t&3]; iter t stages tile t+3 -> buf[(t+3)&3] = buf[(t-1)&3].
//   Reuse safe: all waves' reads of buf[t-1] COMPLETE (per-wave lgkm0 before q2-MM
//   + q2/q3 barriers) before any iter-t stage is issued.
//   Landing: q3 fence vmcnt(8) allows exactly tiles t+2,t+3 (4 loads each) in
//   flight => tile t+1 fully landed before any wave reads it at iter t+1 q0.
// Phases per iter (quadrants Q00,Q01,Q11,Q10; 8 MFMA each):
//   q0: ds_read af0(4)+b0(2) | stage A(t+3) | bar | lgkm0 | MM af0*b0 | bar
//   q1: ds_read b1(2)        | stage B(t+3) | bar | lgkm0 | MM af0*b1 | bar
//   q2: ds_read af1(4)       |                bar | lgkm0 | MM af1*b1 | bar
//   q3:                                                     MM af1*b0 | vm8 bar
// Swizzle: LDS row = 32 bf16 = 4 x 16B slots; phys slot = gslot ^ ((row>>1)&3).
// Stage side: lane l (row l>>2, phys l&3) fetches global slot (l&3)^((l>>3)&3);
// read side: phys = quad ^ ((lr>>1)&3). 16 lanes -> all 8 bank-groups, 2-way (free).
template <int BF16OUT>
__global__ __launch_bounds__(512, 2) void gemm256(
    const unsigned short* __restrict__ A,   // M x K bf16
    const unsigned short* __restrict__ Bt,  // N x K bf16
    const float* __restrict__ bias,         // N fp32
    void* __restrict__ Cout, int M, int N, int K) {
    __shared__ unsigned short As[4][256 * 32];  // 64 KiB
    __shared__ unsigned short Bs[4][256 * 32];  // 64 KiB

    const int n0 = blockIdx.x * 256, m0 = blockIdx.y * 256;
    const int t = threadIdx.x, lane = t & 63, w = t >> 6;
    const int quad = lane >> 4, lr = lane & 15;
    const int wm = (w >> 2) * 128, wn = (w & 3) * 64;

    // staging: one GLL op = 512 threads x 16B = 128 rows x 32 k. Wave w covers
    // rows w*16..w*16+15; lane l -> row_in_16 = l>>2, phys slot = l&3, global
    // slot pre-swizzled = (l&3) ^ ((l>>3)&3)  (rule #21: source-permute + read-
    // permute are the same involution).
    const int sr = lane >> 2;
    const int sc = ((lane & 3) ^ ((lane >> 3) & 3)) * 8;
    const unsigned short* Ag = A + (size_t)(m0 + w * 16 + sr) * K + sc;
    const unsigned short* Bg = Bt + (size_t)(n0 + w * 16 + sr) * K + sc;

    // read-side swizzled slot (elements): phys = quad ^ ((lr>>1)&3)
    const int rsw = (quad ^ ((lr >> 1) & 3)) * 8;

    float4v acc[8][4] = {};
    short8 af0[4], af1[4], b0[2], b1[2];

#define SA(buf, rb, k0) \
    GLL16(Ag + (size_t)(rb) * K + (k0), &As[buf][((rb) + w * 16) * 32])
#define SB(buf, rb, k0) \
    GLL16(Bg + (size_t)(rb) * K + (k0), &Bs[buf][((rb) + w * 16) * 32])
#define STAGE_A(buf, k0) do { SA(buf, 0, k0); SA(buf, 128, k0); } while (0)
#define STAGE_B(buf, k0) do { SB(buf, 0, k0); SB(buf, 128, k0); } while (0)
#define LDA(dst, mh)                                                         \
    do {                                                                     \
        _Pragma("unroll") for (int i = 0; i < 4; ++i)                        \
            dst[i] = *(const short8*)&As[cur][                               \
                (wm + (mh)*64 + i * 16 + lr) * 32 + rsw];                    \
    } while (0)
#define LDB(dst, nh)                                                         \
    do {                                                                     \
        _Pragma("unroll") for (int j = 0; j < 2; ++j)                        \
            dst[j] = *(const short8*)&Bs[cur][                               \
                (wn + (nh)*32 + j * 16 + lr) * 32 + rsw];                    \
    } while (0)
#define MM(ar, br, io, jo)                                                   \
    do {                                                                     \
        __builtin_amdgcn_s_setprio(1);                                       \
        _Pragma("unroll") for (int i = 0; i < 4; ++i)                        \
            _Pragma("unroll") for (int j = 0; j < 2; ++j)                    \
                acc[(io) + i][(jo) + j] = MFMA16(                            \
                    ar[i], br[j], acc[(io) + i][(jo) + j]);                  \
        __builtin_amdgcn_s_setprio(0);                                       \
    } while (0)
#define WAIT_LGKM0()                                                         \
    do {                                                                     \
        asm volatile("s_waitcnt lgkmcnt(0)" ::: "memory");                   \
        __builtin_amdgcn_sched_barrier(0);                                   \
    } while (0)

    const int NT = K >> 5;  // BK=32; K=2048 -> 64 tiles (NT%4==0, NT>=4)
    // prologue: tiles 0,1,2 (4 loads each)
    STAGE_A(0, 0);  STAGE_B(0, 0);
    STAGE_A(1, 32); STAGE_B(1, 32);
    STAGE_A(2, 64); STAGE_B(2, 64);
    asm volatile("s_waitcnt vmcnt(8)" ::: "memory");  // tile 0 landed
    __builtin_amdgcn_s_barrier();

    for (int tk = 0; tk < NT; ++tk) {
        const int cur = tk & 3;
        const int b3 = (tk + 3) & 3;
        int t3 = tk + 3; if (t3 >= NT) t3 -= NT;  // wrap -> dummy re-stage
        const int k3 = t3 << 5;

        // ---- q0: Q00 = af0 x b0 ----
        LDA(af0, 0);
        LDB(b0, 0);
        STAGE_A(b3, k3);
        __builtin_amdgcn_s_barrier();
        WAIT_LGKM0();
        MM(af0, b0, 0, 0);
        __builtin_amdgcn_s_barrier();
        // ---- q1: Q01 = af0 x b1 ----
        LDB(b1, 1);
        STAGE_B(b3, k3);
        __builtin_amdgcn_s_barrier();
        WAIT_LGKM0();
        MM(af0, b1, 0, 2);
        __builtin_amdgcn_s_barrier();
        // ---- q2: Q11 = af1 x b1 ----
        LDA(af1, 1);
        __builtin_amdgcn_s_barrier();
        WAIT_LGKM0();
        MM(af1, b1, 4, 2);
        __builtin_amdgcn_s_barrier();
        // ---- q3: Q10 = af1 x b0 ----
        MM(af1, b0, 4, 0);
        asm volatile("s_waitcnt vmcnt(8)" ::: "memory");  // tile tk+1 landed
        __builtin_amdgcn_s_barrier();
    }
    // drain dummy wrap-around stages before LDS is freed at endpgm
    asm volatile("s_waitcnt vmcnt(0)" ::: "memory");

#pragma unroll
    for (int jj = 0; jj < 4; ++jj) {
        const int n = n0 + wn + jj * 16 + lr;
        const float bv = bias[n];
#pragma unroll
        for (int ii = 0; ii < 8; ++ii)
#pragma unroll
            for (int r = 0; r < 4; ++r) {
                const int m = m0 + wm + ii * 16 + quad * 4 + r;
                const float v = acc[ii][jj][r] + bv;
                if (BF16OUT)
                    ((unsigned short*)Cout)[(size_t)m * N + n] = f2b(v);
                else
                    ((float*)Cout)[(size_t)m * N + n] = v;
            }
    }
#undef SA
#undef SB
#undef STAGE_A
#undef STAGE_B
#undef LDA
#undef LDB
#undef MM
#undef WAIT_LGKM0
}

// ---------------- RoPE in-place on q,k of qkv (bf16), 4 pairs/thread -----------
__global__ void rope_kernel(unsigned short* __restrict__ qkv) {
    int tid = blockIdx.x * 256 + threadIdx.x;  // 2,097,152 threads
    int i4 = tid & 15;
    int h = (tid >> 4) & 15;
    int s = (tid >> 8) & 2047;
    int b = tid >> 19;
    size_t off = ((size_t)(b * SS + s)) * D3 + h * HD + i4 * 8;
    unsigned short* q = qkv + off;
    unsigned short* k = q + 2048;
    short8 qv = *(short8*)q, kv = *(short8*)k;
    const float L2IF = 0.2076205059304601f;    // log2(10000)/64
    const float R2PI = 0.15915494309189535f;   // 1/(2*pi)
    short8 qo, ko;
#pragma unroll
    for (int j = 0; j < 4; ++j) {
        int i = i4 * 4 + j;
        float invr = exp2f(-(float)i * L2IF) * R2PI;
        float rev = (float)s * invr;
        float rr = rev - floorf(rev);
        float sn = __builtin_amdgcn_sinf(rr);
        float cs = __builtin_amdgcn_cosf(rr);
        float a0 = b2f((unsigned short)qv[2 * j]);
        float a1 = b2f((unsigned short)qv[2 * j + 1]);
        qo[2 * j] = (short)f2b(a0 * cs - a1 * sn);
        qo[2 * j + 1] = (short)f2b(a1 * cs + a0 * sn);
        float c0 = b2f((unsigned short)kv[2 * j]);
        float c1 = b2f((unsigned short)kv[2 * j + 1]);
        ko[2 * j] = (short)f2b(c0 * cs - c1 * sn);
        ko[2 * j + 1] = (short)f2b(c1 * cs + c0 * sn);
    }
    *(short8*)q = qo;
    *(short8*)k = ko;
}

// ---------------- flash attention (causal), S^T form, 1-barrier pipeline -------
// grid (8, B*H): block handles q-block pair (x, 15-x) -> uniform 34 k-tiles.
// Ks/Vs double-buffered: prefetch tile i+1 while computing tile i.
__global__ __launch_bounds__(256) void attn_kernel(
    const unsigned short* __restrict__ qkv,
    const unsigned short* __restrict__ vT,
    unsigned short* __restrict__ ctx) {
    __shared__ unsigned short Ks[2][64 * 128];  // [key][dim] swizzled chunks
    __shared__ unsigned short Vs[2][128 * 64];  // [dim][key] swizzled chunks
    __shared__ unsigned short PT[4][32][40];    // per-wave P^T rows=q, 32-key chunk
    const int bh = blockIdx.y, b = bh >> 4, h = bh & 15;
    const int t = threadIdx.x, w = t >> 6, lane = t & 63;
    const int quad = lane >> 4, lr = lane & 15;
    const unsigned short* qbase = qkv + (size_t)b * SS * D3 + h * HD;
    const unsigned short* kbase = qbase + 2048;
    const unsigned short* vtb = vT + (size_t)bh * HD * SS;
    const float SCL2E = 0.12751741769976451f;   // (1/sqrt(128))*log2(e)
    const float NB16 = -23.083120654223414f;    // -16*log2(e)
    const int q0a = blockIdx.x * 128;
    const int q0b = (15 - (int)blockIdx.x) * 128;
    const int nta = (q0a >> 6) + 2, ntb = (q0b >> 6) + 2, ntot = nta + ntb;
    const int kr = lane >> 4, kg = lane & 15;
    const int vr = lane >> 3, vg = lane & 7;

    auto stage = [&](int k0, int bi) {
        unsigned short* KD = Ks[bi];
        unsigned short* VD = Vs[bi];
#pragma unroll
        for (int u = 0; u < 4; ++u) {
            int row = w * 16 + u * 4 + kr;
            int g = kg ^ (row & 15);
            GLL16(kbase + (size_t)(k0 + row) * D3 + g * 8,
                  &KD[(w * 16 + u * 4) * 128]);
        }
#pragma unroll
        for (int u = 0; u < 4; ++u) {
            int row = w * 32 + u * 8 + vr;
            int g = vg ^ (row & 7);
            GLL16(vtb + (size_t)row * SS + k0 + g * 8,
                  &VD[(w * 32 + u * 8) * 64]);
        }
    };

    int wq = q0a + w * 32;
    short8 qf[2][4];
#pragma unroll
    for (int m = 0; m < 2; ++m)
#pragma unroll
        for (int c = 0; c < 4; ++c)
            qf[m][c] = *(const short8*)(qbase + (size_t)(wq + m * 16 + lr) * D3 +
                                        c * 32 + quad * 8);

    float4v o[2][8] = {};
    float l_lane[2] = {0.f, 0.f};

    auto epilogue = [&]() {
#pragma unroll
        for (int m = 0; m < 2; ++m) {
            float l = l_lane[m];
            l += __shfl_xor(l, 16);
            l += __shfl_xor(l, 32);  // all lanes now hold l for q=lr
#pragma unroll
            for (int r = 0; r < 4; ++r) {
                float linv = 1.0f / __shfl(l, quad * 4 + r);
#pragma unroll
                for (int dc = 0; dc < 8; ++dc) {
                    float val = o[m][dc][r] * linv;
                    ctx[(size_t)(b * SS + wq + m * 16 + quad * 4 + r) * DD +
                        h * HD + dc * 16 + lr] = f2b(val);
                }
            }
        }
    };

    stage(0, 0);  // prologue prefetch

    for (int it = 0; it < ntot; ++it) {
        __syncthreads();  // drains stage(it) loads; fences buffer reuse
        int nit = it + 1;
        if (nit < ntot) stage((nit < nta ? nit : nit - nta) * 64, nit & 1);
        int k0 = (it < nta ? it : it - nta) * 64;
        const unsigned short* KB = Ks[it & 1];
        const unsigned short* VB = Vs[it & 1];

        if (k0 <= wq + 31) {
            // S^T = K Q^T : rows=key, cols=q. 4 key-subtiles x 2 q-subtiles.
            float4v sc[2][4] = {};
#pragma unroll
            for (int c = 0; c < 4; ++c) {
                short8 kf[4];
#pragma unroll
                for (int ks = 0; ks < 4; ++ks)
                    kf[ks] = *(const short8*)&KB[(ks * 16 + lr) * 128 +
                                                 (((c * 4 + quad) ^ lr) * 8)];
#pragma unroll
                for (int ks = 0; ks < 4; ++ks) {
                    sc[0][ks] = MFMA16(kf[ks], qf[0][c], sc[0][ks]);
                    sc[1][ks] = MFMA16(kf[ks], qf[1][c], sc[1][ks]);
                }
            }
            const bool nm = (k0 + 63 > wq);
#pragma unroll
            for (int kc = 0; kc < 2; ++kc) {
                // softmax on 32-key chunk; lane holds keys quad*4+r of q=lr
#pragma unroll
                for (int m = 0; m < 2; ++m)
#pragma unroll
                    for (int ks2 = 0; ks2 < 2; ++ks2) {
                        int ks = kc * 2 + ks2;
                        unsigned pk[2];
#pragma unroll
                        for (int rp = 0; rp < 2; ++rp) {
                            unsigned lo = 0, hi = 0;
#pragma unroll
                            for (int rr = 0; rr < 2; ++rr) {
                                int r = rp * 2 + rr;
                                float p = exp2f(fmaf(sc[m][ks][r], SCL2E, NB16));
                                if (nm) {
                                    int key = k0 + ks * 16 + quad * 4 + r;
                                    if (key > wq + m * 16 + lr) p = 0.0f;
                                }
                                l_lane[m] += p;
                                union { float f; unsigned u; } pu;
                                pu.f = p;
                                if (rr == 0) lo = pu.u >> 16;
                                else hi = pu.u >> 16;
                            }
                            pk[rp] = lo | (hi << 16);
                        }
                        uint2 pkk = {pk[0], pk[1]};
                        *(uint2*)&PT[w][m * 16 + lr][ks2 * 16 + quad * 4] = pkk;
                    }
                // O += P V for this 32-key chunk
                short8 pf0 = *(const short8*)&PT[w][lr][quad * 8];
                short8 pf1 = *(const short8*)&PT[w][16 + lr][quad * 8];
#pragma unroll
                for (int dc = 0; dc < 8; ++dc) {
                    short8 vf = *(const short8*)&VB[(dc * 16 + lr) * 64 +
                                                    (((kc * 4 + quad) ^ (lr & 7)) * 8)];
                    o[0][dc] = MFMA16(pf0, vf, o[0][dc]);
                    o[1][dc] = MFMA16(pf1, vf, o[1][dc]);
                }
            }
        }

        if (it == nta - 1) {
            // finish q-block a, switch to q-block b
            epilogue();
#pragma unroll
            for (int m = 0; m < 2; ++m) {
                l_lane[m] = 0.f;
#pragma unroll
                for (int dc = 0; dc < 8; ++dc) o[m][dc] = (float4v){0, 0, 0, 0};
            }
            wq = q0b + w * 32;
#pragma unroll
            for (int m = 0; m < 2; ++m)
#pragma unroll
                for (int c = 0; c < 4; ++c)
                    qf[m][c] = *(const short8*)(qbase +
                                                (size_t)(wq + m * 16 + lr) * D3 +
                                                c * 32 + quad * 8);
        }
    }
    epilogue();
}

extern "C" void kernel_launch(void* const* d_in, const int* in_sizes, int n_in,
                              void* d_out, int out_size, void* d_ws, size_t ws_size,
                              hipStream_t stream) {
    const float* x = (const float*)d_in[0];
    const float* Wqkv_w = (const float*)d_in[2];
    const float* Wqkv_b = (const float*)d_in[3];
    const float* Wout_w = (const float*)d_in[4];
    const float* Wout_b = (const float*)d_in[5];
    float* out = (float*)d_out;

    unsigned short* x_bf = (unsigned short*)d_ws;   // 16,777,216 el (reused as vT)
    unsigned short* wqkv_t = x_bf + 16777216;       // 12,582,912 el
    unsigned short* wout_t = wqkv_t + 12582912;     //  4,194,304 el
    unsigned short* qkv = wout_t + 4194304;         // 50,331,648 el
    unsigned short* ctx = qkv + 50331648;           // 16,777,216 el
    unsigned short* vT = x_bf;                      // alias: x_bf dead after QKV GEMM
    // total ws: 100,663,296 el * 2B = 192 MiB

    cast_f32_bf16<<<16384, 256, 0, stream>>>(x, x_bf);
    transpose_cast<<<dim3(192, 64), 256, 0, stream>>>(Wqkv_w, wqkv_t, 2048, 6144);
    transpose_cast<<<dim3(64, 64), 256, 0, stream>>>(Wout_w, wout_t, 2048, 2048);
    gemm256<1><<<dim3(24, 32), 512, 0, stream>>>(x_bf, wqkv_t, Wqkv_b, qkv,
                                                 8192, 6144, 2048);
    rope_kernel<<<8192, 256, 0, stream>>>(qkv);
    vtrans<<<dim3(64, 4, 64), 256, 0, stream>>>(qkv, vT);
    attn_kernel<<<dim3(8, 64), 256, 0, stream>>>(qkv, vT, ctx);
    gemm256<0><<<dim3(8, 32), 512, 0, stream>>>(ctx, wout_t, Wout_b, out,
                                                8192, 2048, 2048);
}

// Round 5
// 686.004 us; speedup vs baseline: 1.1458x; 1.0747x over previous
//
#include <hip/hip_runtime.h>

#define BB 4
#define SS 2048
#define DD 2048
#define HH 16
#define HD 128
#define D3 6144

typedef __attribute__((ext_vector_type(8))) short short8;
typedef __attribute__((ext_vector_type(4))) float float4v;

#define MFMA16(a, b, c) __builtin_amdgcn_mfma_f32_16x16x32_bf16(a, b, c, 0, 0, 0)

// async global->LDS, 16B per lane; LDS dest = wave-uniform base + lane*16
#define GLL16(g, l)                                                     \
    __builtin_amdgcn_global_load_lds(                                   \
        (__attribute__((address_space(1))) void*)(g),                   \
        (__attribute__((address_space(3))) void*)(l), 16, 0, 0)

__device__ __forceinline__ unsigned short f2b(float f) {
    union { float f; unsigned u; } v;
    v.f = f;
    unsigned r = v.u + 0x7FFFu + ((v.u >> 16) & 1u);  // RNE
    return (unsigned short)(r >> 16);
}
__device__ __forceinline__ float b2f(unsigned short h) {
    union { unsigned u; float f; } v;
    v.u = ((unsigned)h) << 16;
    return v.f;
}

// ---------------- cast fp32 -> bf16 (4 elems/thread) ----------------
__global__ void cast_f32_bf16(const float* __restrict__ in,
                              unsigned short* __restrict__ out) {
    int i = (blockIdx.x * 256 + threadIdx.x) * 4;
    float4 v = *(const float4*)(in + i);
    ushort4 o;
    o.x = f2b(v.x); o.y = f2b(v.y); o.z = f2b(v.z); o.w = f2b(v.w);
    *(ushort4*)(out + i) = o;
}

// ------------- transpose + cast: in (R x C) fp32 -> out (C x R) bf16 -------------
__global__ void transpose_cast(const float* __restrict__ in,
                               unsigned short* __restrict__ out, int R, int C) {
    __shared__ float tile[32][33];
    int c0 = blockIdx.x * 32, r0 = blockIdx.y * 32;
    int tc = threadIdx.x & 31, tr = threadIdx.x >> 5;
#pragma unroll
    for (int i = 0; i < 4; ++i) {
        int r = tr + i * 8;
        tile[r][tc] = in[(size_t)(r0 + r) * C + c0 + tc];
    }
    __syncthreads();
#pragma unroll
    for (int i = 0; i < 4; ++i) {
        int wr = tr + i * 8;
        out[(size_t)(c0 + wr) * R + r0 + tc] = f2b(tile[tc][wr]);
    }
}

// ---------- transpose V within qkv -> vT[bh][d][s] (bf16) ----------
__global__ void vtrans(const unsigned short* __restrict__ qkv,
                       unsigned short* __restrict__ vT) {
    __shared__ unsigned short tile[32][33];
    int bh = blockIdx.z, b = bh >> 4, h = bh & 15;
    int s0 = blockIdx.x * 32, d0 = blockIdx.y * 32;
    int tc = threadIdx.x & 31, tr = threadIdx.x >> 5;
    const unsigned short* src = qkv + (size_t)b * SS * D3 + 4096 + h * HD;
#pragma unroll
    for (int i = 0; i < 4; ++i) {
        int sl = tr + i * 8;
        tile[sl][tc] = src[(size_t)(s0 + sl) * D3 + d0 + tc];
    }
    __syncthreads();
    unsigned short* dst = vT + (size_t)bh * HD * SS;
#pragma unroll
    for (int i = 0; i < 4; ++i) {
        int dl = tr + i * 8;
        dst[(size_t)(d0 + dl) * SS + s0 + tc] = tile[tc][dl];
    }
}

// ============ 256x256 bf16 GEMM, ring-4 pipelined: C = A * Bt^T + bias ============
// 8 waves (2M x 4N), BK=32, 4-deep LDS tile ring (4 x 32 KiB = 128 KiB),
// counted vmcnt(8) once per K-tile (T3/T4), XOR slot-swizzle (T2), setprio (T5).
// 2 phases/iter, 16 MFMA per phase (m201 barrier:MFMA ratio; R4 post-mortem:
// 4 phases x 8 MFMA was sync-rate-bound at MfmaUtil 33%).
//
// Ring ledger (full-tile granularity; uniform across waves; per-wave vmcnt):
//   iter t reads buf[t&3]; iter t stages tile t+3 -> buf[(t+3)&3] = buf[(t-1)&3].
//   Reuse safe: all waves' reads of buf[t-1] COMPLETE (per-wave lgkm0 before p1-MM
//   + p1 closing barrier) before any iter-t stage is issued.
//   Landing: p1 fence vmcnt(8) allows exactly tiles t+2,t+3 (4 ops/wave each) in
//   flight => tile t+1 fully landed (all waves, via barrier) before iter t+1 p0.
// Phases per iter:
//   p0: ds_read af0(4)+b0(2)+b1(2) | stage A(t+3) | bar | lgkm0 | MM af0x{b0,b1} | bar
//   p1: ds_read af1(4)             | stage B(t+3) | bar | lgkm0 | MM af1x{b1,b0} | vm8 bar
// Swizzle: LDS row = 32 bf16 = 4 x 16B slots; phys slot = gslot ^ ((row>>1)&3).
// Stage side: lane l (row l>>2, phys l&3) fetches global slot (l&3)^((l>>3)&3);
// read side: phys = quad ^ ((lr>>1)&3). 16 lanes -> all 8 bank-groups, 2-way (free).
template <int BF16OUT>
__global__ __launch_bounds__(512, 2) void gemm256(
    const unsigned short* __restrict__ A,   // M x K bf16
    const unsigned short* __restrict__ Bt,  // N x K bf16
    const float* __restrict__ bias,         // N fp32
    void* __restrict__ Cout, int M, int N, int K) {
    __shared__ unsigned short As[4][256 * 32];  // 64 KiB
    __shared__ unsigned short Bs[4][256 * 32];  // 64 KiB

    const int n0 = blockIdx.x * 256, m0 = blockIdx.y * 256;
    const int t = threadIdx.x, lane = t & 63, w = t >> 6;
    const int quad = lane >> 4, lr = lane & 15;
    const int wm = (w >> 2) * 128, wn = (w & 3) * 64;

    // staging: one GLL line = 512 threads x 16B = 128 rows x 32 k. Wave w covers
    // rows w*16..w*16+15; lane l -> row_in_16 = l>>2, phys slot = l&3, global
    // slot pre-swizzled = (l&3) ^ ((l>>3)&3)  (rule #21: source-permute + read-
    // permute are the same involution).
    const int sr = lane >> 2;
    const int sc = ((lane & 3) ^ ((lane >> 3) & 3)) * 8;
    const unsigned short* Ag = A + (size_t)(m0 + w * 16 + sr) * K + sc;
    const unsigned short* Bg = Bt + (size_t)(n0 + w * 16 + sr) * K + sc;

    // read-side swizzled slot (elements): phys = quad ^ ((lr>>1)&3)
    const int rsw = (quad ^ ((lr >> 1) & 3)) * 8;

    float4v acc[8][4] = {};
    short8 af0[4], af1[4], b0[2], b1[2];

#define SA(buf, rb, k0) \
    GLL16(Ag + (size_t)(rb) * K + (k0), &As[buf][((rb) + w * 16) * 32])
#define SB(buf, rb, k0) \
    GLL16(Bg + (size_t)(rb) * K + (k0), &Bs[buf][((rb) + w * 16) * 32])
#define STAGE_A(buf, k0) do { SA(buf, 0, k0); SA(buf, 128, k0); } while (0)
#define STAGE_B(buf, k0) do { SB(buf, 0, k0); SB(buf, 128, k0); } while (0)
#define LDA(dst, mh)                                                         \
    do {                                                                     \
        _Pragma("unroll") for (int i = 0; i < 4; ++i)                        \
            dst[i] = *(const short8*)&As[cur][                               \
                (wm + (mh)*64 + i * 16 + lr) * 32 + rsw];                    \
    } while (0)
#define LDB(dst, nh)                                                         \
    do {                                                                     \
        _Pragma("unroll") for (int j = 0; j < 2; ++j)                        \
            dst[j] = *(const short8*)&Bs[cur][                               \
                (wn + (nh)*32 + j * 16 + lr) * 32 + rsw];                    \
    } while (0)
// 8-MFMA quadrant, no setprio (wrapped by MM2)
#define MMQ(ar, br, io, jo)                                                  \
    do {                                                                     \
        _Pragma("unroll") for (int i = 0; i < 4; ++i)                        \
            _Pragma("unroll") for (int j = 0; j < 2; ++j)                    \
                acc[(io) + i][(jo) + j] = MFMA16(                            \
                    ar[i], br[j], acc[(io) + i][(jo) + j]);                  \
    } while (0)
// 16-MFMA phase cluster with one setprio pair (T5)
#define MM2(ar, br0, io, jo0, br1, jo1)                                      \
    do {                                                                     \
        __builtin_amdgcn_s_setprio(1);                                       \
        MMQ(ar, br0, io, jo0);                                               \
        MMQ(ar, br1, io, jo1);                                               \
        __builtin_amdgcn_s_setprio(0);                                       \
    } while (0)
#define WAIT_LGKM0()                                                         \
    do {                                                                     \
        asm volatile("s_waitcnt lgkmcnt(0)" ::: "memory");                   \
        __builtin_amdgcn_sched_barrier(0);                                   \
    } while (0)

    const int NT = K >> 5;  // BK=32; K=2048 -> 64 tiles (NT >= 4)
    // prologue: tiles 0,1,2 (4 ops/wave each)
    STAGE_A(0, 0);  STAGE_B(0, 0);
    STAGE_A(1, 32); STAGE_B(1, 32);
    STAGE_A(2, 64); STAGE_B(2, 64);
    asm volatile("s_waitcnt vmcnt(8)" ::: "memory");  // tile 0 landed
    __builtin_amdgcn_s_barrier();

    for (int tk = 0; tk < NT; ++tk) {
        const int cur = tk & 3;
        const int b3 = (tk + 3) & 3;
        int t3 = tk + 3; if (t3 >= NT) t3 -= NT;  // wrap -> dummy re-stage
        const int k3 = t3 << 5;

        // ---- p0: 16 MFMA, af0 x {b0,b1} ----
        LDA(af0, 0);
        LDB(b0, 0);
        LDB(b1, 1);
        STAGE_A(b3, k3);
        __builtin_amdgcn_s_barrier();
        WAIT_LGKM0();
        MM2(af0, b0, 0, 0, b1, 2);
        __builtin_amdgcn_s_barrier();
        // ---- p1: 16 MFMA, af1 x {b1,b0} ----
        LDA(af1, 1);
        STAGE_B(b3, k3);
        __builtin_amdgcn_s_barrier();
        WAIT_LGKM0();
        MM2(af1, b1, 4, 2, b0, 0);
        asm volatile("s_waitcnt vmcnt(8)" ::: "memory");  // tile tk+1 landed
        __builtin_amdgcn_s_barrier();
    }
    // drain dummy wrap-around stages before LDS is freed at endpgm
    asm volatile("s_waitcnt vmcnt(0)" ::: "memory");

#pragma unroll
    for (int jj = 0; jj < 4; ++jj) {
        const int n = n0 + wn + jj * 16 + lr;
        const float bv = bias[n];
#pragma unroll
        for (int ii = 0; ii < 8; ++ii)
#pragma unroll
            for (int r = 0; r < 4; ++r) {
                const int m = m0 + wm + ii * 16 + quad * 4 + r;
                const float v = acc[ii][jj][r] + bv;
                if (BF16OUT)
                    ((unsigned short*)Cout)[(size_t)m * N + n] = f2b(v);
                else
                    ((float*)Cout)[(size_t)m * N + n] = v;
            }
    }
#undef SA
#undef SB
#undef STAGE_A
#undef STAGE_B
#undef LDA
#undef LDB
#undef MMQ
#undef MM2
#undef WAIT_LGKM0
}

// ---------------- RoPE in-place on q,k of qkv (bf16), 4 pairs/thread -----------
__global__ void rope_kernel(unsigned short* __restrict__ qkv) {
    int tid = blockIdx.x * 256 + threadIdx.x;  // 2,097,152 threads
    int i4 = tid & 15;
    int h = (tid >> 4) & 15;
    int s = (tid >> 8) & 2047;
    int b = tid >> 19;
    size_t off = ((size_t)(b * SS + s)) * D3 + h * HD + i4 * 8;
    unsigned short* q = qkv + off;
    unsigned short* k = q + 2048;
    short8 qv = *(short8*)q, kv = *(short8*)k;
    const float L2IF = 0.2076205059304601f;    // log2(10000)/64
    const float R2PI = 0.15915494309189535f;   // 1/(2*pi)
    short8 qo, ko;
#pragma unroll
    for (int j = 0; j < 4; ++j) {
        int i = i4 * 4 + j;
        float invr = exp2f(-(float)i * L2IF) * R2PI;
        float rev = (float)s * invr;
        float rr = rev - floorf(rev);
        float sn = __builtin_amdgcn_sinf(rr);
        float cs = __builtin_amdgcn_cosf(rr);
        float a0 = b2f((unsigned short)qv[2 * j]);
        float a1 = b2f((unsigned short)qv[2 * j + 1]);
        qo[2 * j] = (short)f2b(a0 * cs - a1 * sn);
        qo[2 * j + 1] = (short)f2b(a1 * cs + a0 * sn);
        float c0 = b2f((unsigned short)kv[2 * j]);
        float c1 = b2f((unsigned short)kv[2 * j + 1]);
        ko[2 * j] = (short)f2b(c0 * cs - c1 * sn);
        ko[2 * j + 1] = (short)f2b(c1 * cs + c0 * sn);
    }
    *(short8*)q = qo;
    *(short8*)k = ko;
}

// ---------------- flash attention (causal), S^T form, 1-barrier pipeline -------
// grid (8, B*H): block handles q-block pair (x, 15-x) -> uniform 34 k-tiles.
// Ks/Vs double-buffered: prefetch tile i+1 while computing tile i.
__global__ __launch_bounds__(256) void attn_kernel(
    const unsigned short* __restrict__ qkv,
    const unsigned short* __restrict__ vT,
    unsigned short* __restrict__ ctx) {
    __shared__ unsigned short Ks[2][64 * 128];  // [key][dim] swizzled chunks
    __shared__ unsigned short Vs[2][128 * 64];  // [dim][key] swizzled chunks
    __shared__ unsigned short PT[4][32][40];    // per-wave P^T rows=q, 32-key chunk
    const int bh = blockIdx.y, b = bh >> 4, h = bh & 15;
    const int t = threadIdx.x, w = t >> 6, lane = t & 63;
    const int quad = lane >> 4, lr = lane & 15;
    const unsigned short* qbase = qkv + (size_t)b * SS * D3 + h * HD;
    const unsigned short* kbase = qbase + 2048;
    const unsigned short* vtb = vT + (size_t)bh * HD * SS;
    const float SCL2E = 0.12751741769976451f;   // (1/sqrt(128))*log2(e)
    const float NB16 = -23.083120654223414f;    // -16*log2(e)
    const int q0a = blockIdx.x * 128;
    const int q0b = (15 - (int)blockIdx.x) * 128;
    const int nta = (q0a >> 6) + 2, ntb = (q0b >> 6) + 2, ntot = nta + ntb;
    const int kr = lane >> 4, kg = lane & 15;
    const int vr = lane >> 3, vg = lane & 7;

    auto stage = [&](int k0, int bi) {
        unsigned short* KD = Ks[bi];
        unsigned short* VD = Vs[bi];
#pragma unroll
        for (int u = 0; u < 4; ++u) {
            int row = w * 16 + u * 4 + kr;
            int g = kg ^ (row & 15);
            GLL16(kbase + (size_t)(k0 + row) * D3 + g * 8,
                  &KD[(w * 16 + u * 4) * 128]);
        }
#pragma unroll
        for (int u = 0; u < 4; ++u) {
            int row = w * 32 + u * 8 + vr;
            int g = vg ^ (row & 7);
            GLL16(vtb + (size_t)row * SS + k0 + g * 8,
                  &VD[(w * 32 + u * 8) * 64]);
        }
    };

    int wq = q0a + w * 32;
    short8 qf[2][4];
#pragma unroll
    for (int m = 0; m < 2; ++m)
#pragma unroll
        for (int c = 0; c < 4; ++c)
            qf[m][c] = *(const short8*)(qbase + (size_t)(wq + m * 16 + lr) * D3 +
                                        c * 32 + quad * 8);

    float4v o[2][8] = {};
    float l_lane[2] = {0.f, 0.f};

    auto epilogue = [&]() {
#pragma unroll
        for (int m = 0; m < 2; ++m) {
            float l = l_lane[m];
            l += __shfl_xor(l, 16);
            l += __shfl_xor(l, 32);  // all lanes now hold l for q=lr
#pragma unroll
            for (int r = 0; r < 4; ++r) {
                float linv = 1.0f / __shfl(l, quad * 4 + r);
#pragma unroll
                for (int dc = 0; dc < 8; ++dc) {
                    float val = o[m][dc][r] * linv;
                    ctx[(size_t)(b * SS + wq + m * 16 + quad * 4 + r) * DD +
                        h * HD + dc * 16 + lr] = f2b(val);
                }
            }
        }
    };

    stage(0, 0);  // prologue prefetch

    for (int it = 0; it < ntot; ++it) {
        __syncthreads();  // drains stage(it) loads; fences buffer reuse
        int nit = it + 1;
        if (nit < ntot) stage((nit < nta ? nit : nit - nta) * 64, nit & 1);
        int k0 = (it < nta ? it : it - nta) * 64;
        const unsigned short* KB = Ks[it & 1];
        const unsigned short* VB = Vs[it & 1];

        if (k0 <= wq + 31) {
            // S^T = K Q^T : rows=key, cols=q. 4 key-subtiles x 2 q-subtiles.
            float4v sc[2][4] = {};
#pragma unroll
            for (int c = 0; c < 4; ++c) {
                short8 kf[4];
#pragma unroll
                for (int ks = 0; ks < 4; ++ks)
                    kf[ks] = *(const short8*)&KB[(ks * 16 + lr) * 128 +
                                                 (((c * 4 + quad) ^ lr) * 8)];
#pragma unroll
                for (int ks = 0; ks < 4; ++ks) {
                    sc[0][ks] = MFMA16(kf[ks], qf[0][c], sc[0][ks]);
                    sc[1][ks] = MFMA16(kf[ks], qf[1][c], sc[1][ks]);
                }
            }
            const bool nm = (k0 + 63 > wq);
#pragma unroll
            for (int kc = 0; kc < 2; ++kc) {
                // softmax on 32-key chunk; lane holds keys quad*4+r of q=lr
#pragma unroll
                for (int m = 0; m < 2; ++m)
#pragma unroll
                    for (int ks2 = 0; ks2 < 2; ++ks2) {
                        int ks = kc * 2 + ks2;
                        unsigned pk[2];
#pragma unroll
                        for (int rp = 0; rp < 2; ++rp) {
                            unsigned lo = 0, hi = 0;
#pragma unroll
                            for (int rr = 0; rr < 2; ++rr) {
                                int r = rp * 2 + rr;
                                float p = exp2f(fmaf(sc[m][ks][r], SCL2E, NB16));
                                if (nm) {
                                    int key = k0 + ks * 16 + quad * 4 + r;
                                    if (key > wq + m * 16 + lr) p = 0.0f;
                                }
                                l_lane[m] += p;
                                union { float f; unsigned u; } pu;
                                pu.f = p;
                                if (rr == 0) lo = pu.u >> 16;
                                else hi = pu.u >> 16;
                            }
                            pk[rp] = lo | (hi << 16);
                        }
                        uint2 pkk = {pk[0], pk[1]};
                        *(uint2*)&PT[w][m * 16 + lr][ks2 * 16 + quad * 4] = pkk;
                    }
                // O += P V for this 32-key chunk
                short8 pf0 = *(const short8*)&PT[w][lr][quad * 8];
                short8 pf1 = *(const short8*)&PT[w][16 + lr][quad * 8];
#pragma unroll
                for (int dc = 0; dc < 8; ++dc) {
                    short8 vf = *(const short8*)&VB[(dc * 16 + lr) * 64 +
                                                    (((kc * 4 + quad) ^ (lr & 7)) * 8)];
                    o[0][dc] = MFMA16(pf0, vf, o[0][dc]);
                    o[1][dc] = MFMA16(pf1, vf, o[1][dc]);
                }
            }
        }

        if (it == nta - 1) {
            // finish q-block a, switch to q-block b
            epilogue();
#pragma unroll
            for (int m = 0; m < 2; ++m) {
                l_lane[m] = 0.f;
#pragma unroll
                for (int dc = 0; dc < 8; ++dc) o[m][dc] = (float4v){0, 0, 0, 0};
            }
            wq = q0b + w * 32;
#pragma unroll
            for (int m = 0; m < 2; ++m)
#pragma unroll
                for (int c = 0; c < 4; ++c)
                    qf[m][c] = *(const short8*)(qbase +
                                                (size_t)(wq + m * 16 + lr) * D3 +
                                                c * 32 + quad * 8);
        }
    }
    epilogue();
}

extern "C" void kernel_launch(void* const* d_in, const int* in_sizes, int n_in,
                              void* d_out, int out_size, void* d_ws, size_t ws_size,
                              hipStream_t stream) {
    const float* x = (const float*)d_in[0];
    const float* Wqkv_w = (const float*)d_in[2];
    const float* Wqkv_b = (const float*)d_in[3];
    const float* Wout_w = (const float*)d_in[4];
    const float* Wout_b = (const float*)d_in[5];
    float* out = (float*)d_out;

    unsigned short* x_bf = (unsigned short*)d_ws;   // 16,777,216 el (reused as vT)
    unsigned short* wqkv_t = x_bf + 16777216;       // 12,582,912 el
    unsigned short* wout_t = wqkv_t + 12582912;     //  4,194,304 el
    unsigned short* qkv = wout_t + 4194304;         // 50,331,648 el
    unsigned short* ctx = qkv + 50331648;           // 16,777,216 el
    unsigned short* vT = x_bf;                      // alias: x_bf dead after QKV GEMM
    // total ws: 100,663,296 el * 2B = 192 MiB

    cast_f32_bf16<<<16384, 256, 0, stream>>>(x, x_bf);
    transpose_cast<<<dim3(192, 64), 256, 0, stream>>>(Wqkv_w, wqkv_t, 2048, 6144);
    transpose_cast<<<dim3(64, 64), 256, 0, stream>>>(Wout_w, wout_t, 2048, 2048);
    gemm256<1><<<dim3(24, 32), 512, 0, stream>>>(x_bf, wqkv_t, Wqkv_b, qkv,
                                                 8192, 6144, 2048);
    rope_kernel<<<8192, 256, 0, stream>>>(qkv);
    vtrans<<<dim3(64, 4, 64), 256, 0, stream>>>(qkv, vT);
    attn_kernel<<<dim3(8, 64), 256, 0, stream>>>(qkv, vT, ctx);
    gemm256<0><<<dim3(8, 32), 512, 0, stream>>>(ctx, wout_t, Wout_b, out,
                                                8192, 2048, 2048);
}